// Round 2
// baseline (629.343 us; speedup 1.0000x reference)
//
#include <hip/hip_runtime.h>

// Problem constants
#define NN 50000
#define EE 800000
#define FF 256   // IN = HID = PROJ = 256
#define NBLK 196 // ceil(NN/256)

typedef float    f32x4 __attribute__((ext_vector_type(4)));
typedef _Float16 f16x8 __attribute__((ext_vector_type(8)));
typedef _Float16 f16x4 __attribute__((ext_vector_type(4)));

// ---------------------------------------------------------------------------
// CSR build kernels (unchanged)
// ---------------------------------------------------------------------------

__global__ void count_kernel(const int* __restrict__ ei, int* __restrict__ ec) {
    int e = blockIdx.x * 256 + threadIdx.x;
    if (e < EE) atomicAdd(&ec[ei[EE + e]], 1);
}

__global__ __launch_bounds__(256) void scan_part(const int* __restrict__ ec,
                                                 int* __restrict__ bsum) {
    int i = blockIdx.x * 256 + threadIdx.x;
    int v = (i < NN) ? ec[i] : 0;
#pragma unroll
    for (int d = 1; d < 64; d <<= 1) v += __shfl_xor(v, d);
    __shared__ int wt[4];
    int lane = threadIdx.x & 63, wid = threadIdx.x >> 6;
    if (lane == 0) wt[wid] = v;
    __syncthreads();
    if (threadIdx.x == 0)
        bsum[blockIdx.x] = wt[0] + wt[1] + wt[2] + wt[3];
}

__global__ __launch_bounds__(256) void scan_mid(const int* __restrict__ bsum,
                                                int* __restrict__ boff,
                                                int* __restrict__ rs) {
    const int t = threadIdx.x;
    int v = (t < NBLK) ? bsum[t] : 0;
    int lane = t & 63, wid = t >> 6;
    int x = v;
#pragma unroll
    for (int d = 1; d < 64; d <<= 1) {
        int u = __shfl_up(x, d);
        if (lane >= d) x += u;
    }
    __shared__ int wt[4];
    if (lane == 63) wt[wid] = x;
    __syncthreads();
    int add = 0;
    for (int wi = 0; wi < wid; ++wi) add += wt[wi];
    x += add;                                   // inclusive scan
    if (t < NBLK) boff[t] = x - v;              // exclusive
    if (t == NBLK - 1) rs[NN] = x;              // total == EE
}

__global__ __launch_bounds__(256) void scan_final(const int* __restrict__ ec,
                                                  const int* __restrict__ boff,
                                                  int* __restrict__ rs,
                                                  float* __restrict__ dinv) {
    int i = blockIdx.x * 256 + threadIdx.x;
    int v = (i < NN) ? ec[i] : 0;
    int lane = threadIdx.x & 63, wid = threadIdx.x >> 6;
    int x = v;
#pragma unroll
    for (int d = 1; d < 64; d <<= 1) {
        int u = __shfl_up(x, d);
        if (lane >= d) x += u;
    }
    __shared__ int wt[4];
    if (lane == 63) wt[wid] = x;
    __syncthreads();
    int add = 0;
    for (int wi = 0; wi < wid; ++wi) add += wt[wi];
    x += add;                                   // block-inclusive
    if (i < NN) {
        rs[i]   = x - v + boff[blockIdx.x];     // global exclusive
        dinv[i] = rsqrtf((float)(v + 1));       // deg = edges + self-loop
    }
}

__global__ void fill_kernel(const int* __restrict__ ei, const int* __restrict__ rs,
                            int* __restrict__ cnt, const float* __restrict__ dinv,
                            int2* __restrict__ ecw) {
    int e = blockIdx.x * 256 + threadIdx.x;
    if (e >= EE) return;
    int s = ei[e];
    int d = ei[EE + e];
    int p = rs[d] + atomicAdd(&cnt[d], 1);
    ecw[p] = make_int2(s, __float_as_int(dinv[s]));
}

// ---------------------------------------------------------------------------
// W pack: swizzled LDS-image (unchanged from round 1)
// ---------------------------------------------------------------------------
__global__ void packw_kernel(const float* __restrict__ W1, const float* __restrict__ W2,
                             _Float16* __restrict__ wp) {
    int idx = blockIdx.x * 256 + threadIdx.x;   // 0..16383
    int p   = idx & 511;
    int kt  = (idx >> 9) & 7;
    int nb  = (idx >> 12) & 1;
    int L   = (idx >> 13) & 1;
    const float* W = L ? W2 : W1;
    int rs = p >> 2, cs = p & 3;
    int r  = rs ^ ((rs >> 2) & 1);
    int c  = cs ^ (r & 3);
    int n  = nb * 128 + r;
    int k0 = kt * 32 + c * 8;
    f16x8 hi, lo;
#pragma unroll
    for (int j = 0; j < 8; ++j) {
        float v = W[(size_t)(k0 + j) * 256 + n];
        _Float16 h = (_Float16)v;
        hi[j] = h;
        lo[j] = (_Float16)(v - (float)h);
    }
    size_t ch = ((size_t)((L * 2 + 0) * 2 + nb) * 8 + kt) * 4096;
    size_t cl = ((size_t)((L * 2 + 1) * 2 + nb) * 8 + kt) * 4096;
    *(f16x8*)(wp + ch + (size_t)p * 8) = hi;
    *(f16x8*)(wp + cl + (size_t)p * 8) = lo;
}

// ---------------------------------------------------------------------------
// GEMM (structure unchanged from round 1; grid re-linearized so the two
// nb-blocks sharing an A panel land on the SAME XCD under round-robin
// dispatch: gid = (p%8) + 16*(p/8) + 8*nb  ->  both members have gid%8 == p%8)
// ---------------------------------------------------------------------------

__device__ __forceinline__ void gll16(const void* g, void* l) {
    __builtin_amdgcn_global_load_lds(
        (const __attribute__((address_space(1))) void*)g,
        (__attribute__((address_space(3))) void*)l, 16, 0, 0);
}

template<typename AT>
__global__ __launch_bounds__(512) void gemm_kernel(
    const AT* __restrict__ X, const _Float16* __restrict__ Bhi,
    const _Float16* __restrict__ Blo, _Float16* __restrict__ H) {
    __shared__ __align__(16) _Float16 Bh[2][4096];   // 2 x 8KB
    __shared__ __align__(16) _Float16 Bl[2][4096];   // 2 x 8KB
    __shared__ __align__(16) AT       As[2][4096];   // fp32: 2x16KB, fp16: 2x8KB

    // de-swizzle linear block id -> (pair p, member nb) with same-XCD pairing
    const int gid = blockIdx.x;
    const int p_  = (gid >> 4) * 8 + (gid & 7);
    const int nb  = (gid >> 3) & 1;
    if (p_ >= 391) return;

    const int tid = threadIdx.x;
    const int ln  = tid & 63;
    const int w   = tid >> 6;        // 0..7
    const int wm  = w & 1;           // 2 x 64 rows
    const int wn  = w >> 1;          // 4 x 32 cols
    const int q   = ln >> 4;         // k-group
    const int l16 = ln & 15;
    const int m0  = p_ * 128;
    const size_t bchunk = (size_t)nb * 8 * 4096;

    f32x4 acc[4][2] = {};            // [mt][nt]

    auto stage = [&](int kt, int buf) {
        int g = w * 64 + ln;                       // granule 0..511
        gll16(Bhi + bchunk + (size_t)kt * 4096 + (size_t)g * 8,
              &Bh[buf][w * 512]);
        gll16(Blo + bchunk + (size_t)kt * 4096 + (size_t)g * 8,
              &Bl[buf][w * 512]);
        if constexpr (sizeof(AT) == 4) {
#pragma unroll
            for (int pp = 0; pp < 2; ++pp) {
                int gg = pp * 512 + w * 64 + ln;    // 0..1023
                int rss = gg >> 3, cs = gg & 7;
                int c  = cs ^ (rss & 7);
                int gm = m0 + rss; if (gm > NN - 1) gm = NN - 1;
                gll16((const float*)X + (size_t)gm * FF + kt * 32 + c * 4,
                      (float*)&As[buf][0] + (size_t)(pp * 512 + w * 64) * 4);
            }
        } else {
            int rss = g >> 2, cs = g & 3;
            int r  = rss ^ ((rss >> 2) & 1);
            int c  = cs ^ (r & 3);
            int gm = m0 + r; if (gm > NN - 1) gm = NN - 1;
            gll16((const _Float16*)X + (size_t)gm * FF + kt * 32 + c * 8,
                  (_Float16*)&As[buf][0] + (size_t)(w * 64) * 8);
        }
    };

    auto compute = [&](int buf) {
        f16x8 af[4], bhf[2], blf[2];
#pragma unroll
        for (int mt = 0; mt < 4; ++mt) {
            int r = wm * 64 + mt * 16 + l16;
            if constexpr (sizeof(AT) == 4) {
                const float* Ab = (const float*)&As[buf][0];
                f32x4 v0 = *(const f32x4*)(Ab + (size_t)(r * 8 + ((2 * q)     ^ (r & 7))) * 4);
                f32x4 v1 = *(const f32x4*)(Ab + (size_t)(r * 8 + ((2 * q + 1) ^ (r & 7))) * 4);
                f16x8 a;
                a[0] = (_Float16)v0.x; a[1] = (_Float16)v0.y;
                a[2] = (_Float16)v0.z; a[3] = (_Float16)v0.w;
                a[4] = (_Float16)v1.x; a[5] = (_Float16)v1.y;
                a[6] = (_Float16)v1.z; a[7] = (_Float16)v1.w;
                af[mt] = a;
            } else {
                const _Float16* Ab = (const _Float16*)&As[buf][0];
                int rr = r ^ ((r >> 2) & 1);
                af[mt] = *(const f16x8*)(Ab + (size_t)(rr * 4 + (q ^ (r & 3))) * 8);
            }
        }
#pragma unroll
        for (int nt = 0; nt < 2; ++nt) {
            int r  = wn * 32 + nt * 16 + l16;
            int rr = r ^ ((r >> 2) & 1);
            int off = (rr * 4 + (q ^ (r & 3))) * 8;
            bhf[nt] = *(const f16x8*)(&Bh[buf][off]);
            blf[nt] = *(const f16x8*)(&Bl[buf][off]);
        }
#pragma unroll
        for (int mt = 0; mt < 4; ++mt)
#pragma unroll
            for (int nt = 0; nt < 2; ++nt) {
                acc[mt][nt] = __builtin_amdgcn_mfma_f32_16x16x32_f16(af[mt], bhf[nt], acc[mt][nt], 0, 0, 0);
                acc[mt][nt] = __builtin_amdgcn_mfma_f32_16x16x32_f16(af[mt], blf[nt], acc[mt][nt], 0, 0, 0);
            }
    };

    stage(0, 0);
    __syncthreads();
    int cur = 0;
#pragma unroll
    for (int kt = 0; kt < 8; ++kt) {
        if (kt < 7) stage(kt + 1, cur ^ 1);
        compute(cur);
        __syncthreads();
        cur ^= 1;
    }

#pragma unroll
    for (int mt = 0; mt < 4; ++mt)
#pragma unroll
        for (int r4 = 0; r4 < 4; ++r4) {
            int m = m0 + wm * 64 + mt * 16 + q * 4 + r4;
            if (m < NN) {
#pragma unroll
                for (int nt = 0; nt < 2; ++nt) {
                    int n = nb * 128 + wn * 32 + nt * 16 + l16;
                    H[(size_t)m * FF + n] = (_Float16)acc[mt][nt][r4];
                }
            }
        }
}

// ---------------------------------------------------------------------------
// Aggregation + bias + PReLU, XCD-resident feature slicing.
// slice = blockIdx & 7  ->  under round-robin dispatch each XCD only gathers
// from its own 3.2 MB H-slice, which stays L2-resident (4 MB/XCD).
// One wave per dst row per slice: 8 edge-groups x 8 lanes (f16x4 = 4 feats).
// ecw read nontemporally (streamed, don't pollute L2); gather reads cached.
// Cross-group reduce via __shfl_xor(8,16,32); lanes 0..7 write the slice.
// ---------------------------------------------------------------------------
template<typename OT>
__global__ __launch_bounds__(256) void agg_kernel(
    const _Float16* __restrict__ H, const int* __restrict__ rs,
    const int2* __restrict__ ecw, const float* __restrict__ dinv,
    const float* __restrict__ bias, const float* __restrict__ a_ptr,
    OT* __restrict__ out) {
    const int slice = blockIdx.x & 7;
    const int row   = (blockIdx.x >> 3) * 4 + (threadIdx.x >> 6);
    if (row >= NN) return;
    const int lane = threadIdx.x & 63;
    const int g    = lane >> 3;          // edge group 0..7
    const int t    = lane & 7;           // feature quad within slice
    const int f0   = slice * 32 + t * 4;

    const float av = a_ptr[0];
    const float di = dinv[row];

    float ax = 0.f, ay = 0.f, az = 0.f, aw = 0.f;
    if (g == 0) {                        // self-loop term, counted once
        f16x4 hv = *(const f16x4*)(H + (size_t)row * FF + f0);
        ax = di * (float)hv.x; ay = di * (float)hv.y;
        az = di * (float)hv.z; aw = di * (float)hv.w;
    }

    int e = rs[row] + g;
    const int end = rs[row + 1];
    if (e < end) {
        long long pv = __builtin_nontemporal_load((const long long*)(ecw + e));
        while (true) {
            e += 8;
            const bool more = (e < end);
            long long pn = 0;
            if (more) pn = __builtin_nontemporal_load((const long long*)(ecw + e));
            int   src = (int)(unsigned)(pv & 0xffffffffLL);
            float w0  = __int_as_float((int)(pv >> 32));
            f16x4 h0  = *(const f16x4*)(H + (size_t)src * FF + f0);
            ax += w0 * (float)h0.x;
            ay += w0 * (float)h0.y;
            az += w0 * (float)h0.z;
            aw += w0 * (float)h0.w;
            if (!more) break;
            pv = pn;
        }
    }

    // reduce across the 8 edge-groups (lanes differing in bits 3..5)
#pragma unroll
    for (int d = 8; d < 64; d <<= 1) {
        ax += __shfl_xor(ax, d);
        ay += __shfl_xor(ay, d);
        az += __shfl_xor(az, d);
        aw += __shfl_xor(aw, d);
    }

    if (g == 0) {
        f32x4 bv = *(const f32x4*)(bias + f0);
        float r0 = di * ax + bv.x; r0 = (r0 >= 0.f) ? r0 : av * r0;
        float r1 = di * ay + bv.y; r1 = (r1 >= 0.f) ? r1 : av * r1;
        float r2 = di * az + bv.z; r2 = (r2 >= 0.f) ? r2 : av * r2;
        float r3 = di * aw + bv.w; r3 = (r3 >= 0.f) ? r3 : av * r3;
        if constexpr (sizeof(OT) == 4) {
            f32x4 res = {r0, r1, r2, r3};
            *(f32x4*)((float*)out + (size_t)row * FF + f0) = res;
        } else {
            f16x4 res;
            res.x = (_Float16)r0; res.y = (_Float16)r1;
            res.z = (_Float16)r2; res.w = (_Float16)r3;
            *(f16x4*)((_Float16*)out + (size_t)row * FF + f0) = res;
        }
    }
}

// ---------------------------------------------------------------------------
// Launch
// ---------------------------------------------------------------------------
extern "C" void kernel_launch(void* const* d_in, const int* in_sizes, int n_in,
                              void* d_out, int out_size, void* d_ws, size_t ws_size,
                              hipStream_t stream) {
    const float* x  = (const float*)d_in[0];
    const float* W1 = (const float*)d_in[1];
    const float* b1 = (const float*)d_in[2];
    const float* W2 = (const float*)d_in[3];
    const float* b2 = (const float*)d_in[4];
    const float* a  = (const float*)d_in[5];
    const int*   ei = (const int*)d_in[6];
    float* out = (float*)d_out;

    char* ws = (char*)d_ws;
    size_t off = 0;
    auto carve = [&](size_t bytes) -> char* {
        char* p = ws + off;
        off = (off + bytes + 255) & ~(size_t)255;
        return p;
    };
    int*      ec   = (int*)carve((size_t)NN * 4);
    int*      cnt  = (int*)carve((size_t)NN * 4);
    int*      rs   = (int*)carve((size_t)(NN + 1) * 4);
    float*    dinv = (float*)carve((size_t)NN * 4);
    int*      bsum = (int*)carve((size_t)NBLK * 4);
    int*      boff = (int*)carve((size_t)NBLK * 4);
    int2*     ecw  = (int2*)carve((size_t)EE * 8);
    _Float16* wp   = (_Float16*)carve((size_t)4 * 65536 * 2);
    _Float16* h    = (_Float16*)carve((size_t)NN * FF * 2);
    _Float16* h1   = (_Float16*)carve((size_t)NN * FF * 2);

    hipMemsetAsync(ec, 0, (size_t)NN * 4, stream);
    hipMemsetAsync(cnt, 0, (size_t)NN * 4, stream);

    count_kernel<<<(EE + 255) / 256, 256, 0, stream>>>(ei, ec);
    scan_part <<<NBLK, 256, 0, stream>>>(ec, bsum);
    scan_mid  <<<1, 256, 0, stream>>>(bsum, boff, rs);
    scan_final<<<NBLK, 256, 0, stream>>>(ec, boff, rs, dinv);
    fill_kernel<<<(EE + 255) / 256, 256, 0, stream>>>(ei, rs, cnt, dinv, ecw);
    packw_kernel<<<64, 256, 0, stream>>>(W1, W2, wp);

    // layer 1: GEMM (fp32 A) -> agg (fp16 out, feeds GEMM2)
    gemm_kernel<float><<<784, 512, 0, stream>>>(x, wp, wp + 65536, h);
    agg_kernel<_Float16><<<12500 * 8, 256, 0, stream>>>(h, rs, ecw, dinv, b1, a, h1);
    // layer 2: GEMM (fp16 A) -> agg (fp32 out, final)
    gemm_kernel<_Float16><<<784, 512, 0, stream>>>(h1, wp + 131072, wp + 131072 + 65536, h);
    agg_kernel<float><<<12500 * 8, 256, 0, stream>>>(h, rs, ecw, dinv, b2, a, out);
}

// Round 3
// 490.247 us; speedup vs baseline: 1.2837x; 1.2837x over previous
//
#include <hip/hip_runtime.h>

// Problem constants
#define NN 50000
#define EE 800000
#define FF 256   // IN = HID = PROJ = 256
#define NBLK 196 // ceil(NN/256)

typedef float    f32x4 __attribute__((ext_vector_type(4)));
typedef _Float16 f16x8 __attribute__((ext_vector_type(8)));
typedef _Float16 f16x4 __attribute__((ext_vector_type(4)));

// ---------------------------------------------------------------------------
// CSR build kernels (unchanged)
// ---------------------------------------------------------------------------

__global__ void count_kernel(const int* __restrict__ ei, int* __restrict__ ec) {
    int e = blockIdx.x * 256 + threadIdx.x;
    if (e < EE) atomicAdd(&ec[ei[EE + e]], 1);
}

__global__ __launch_bounds__(256) void scan_part(const int* __restrict__ ec,
                                                 int* __restrict__ bsum) {
    int i = blockIdx.x * 256 + threadIdx.x;
    int v = (i < NN) ? ec[i] : 0;
#pragma unroll
    for (int d = 1; d < 64; d <<= 1) v += __shfl_xor(v, d);
    __shared__ int wt[4];
    int lane = threadIdx.x & 63, wid = threadIdx.x >> 6;
    if (lane == 0) wt[wid] = v;
    __syncthreads();
    if (threadIdx.x == 0)
        bsum[blockIdx.x] = wt[0] + wt[1] + wt[2] + wt[3];
}

__global__ __launch_bounds__(256) void scan_mid(const int* __restrict__ bsum,
                                                int* __restrict__ boff,
                                                int* __restrict__ rs) {
    const int t = threadIdx.x;
    int v = (t < NBLK) ? bsum[t] : 0;
    int lane = t & 63, wid = t >> 6;
    int x = v;
#pragma unroll
    for (int d = 1; d < 64; d <<= 1) {
        int u = __shfl_up(x, d);
        if (lane >= d) x += u;
    }
    __shared__ int wt[4];
    if (lane == 63) wt[wid] = x;
    __syncthreads();
    int add = 0;
    for (int wi = 0; wi < wid; ++wi) add += wt[wi];
    x += add;                                   // inclusive scan
    if (t < NBLK) boff[t] = x - v;              // exclusive
    if (t == NBLK - 1) rs[NN] = x;              // total == EE
}

__global__ __launch_bounds__(256) void scan_final(const int* __restrict__ ec,
                                                  const int* __restrict__ boff,
                                                  int* __restrict__ rs,
                                                  float* __restrict__ dinv) {
    int i = blockIdx.x * 256 + threadIdx.x;
    int v = (i < NN) ? ec[i] : 0;
    int lane = threadIdx.x & 63, wid = threadIdx.x >> 6;
    int x = v;
#pragma unroll
    for (int d = 1; d < 64; d <<= 1) {
        int u = __shfl_up(x, d);
        if (lane >= d) x += u;
    }
    __shared__ int wt[4];
    if (lane == 63) wt[wid] = x;
    __syncthreads();
    int add = 0;
    for (int wi = 0; wi < wid; ++wi) add += wt[wi];
    x += add;                                   // block-inclusive
    if (i < NN) {
        rs[i]   = x - v + boff[blockIdx.x];     // global exclusive
        dinv[i] = rsqrtf((float)(v + 1));       // deg = edges + self-loop
    }
}

__global__ void fill_kernel(const int* __restrict__ ei, const int* __restrict__ rs,
                            int* __restrict__ cnt, const float* __restrict__ dinv,
                            int2* __restrict__ ecw) {
    int e = blockIdx.x * 256 + threadIdx.x;
    if (e >= EE) return;
    int s = ei[e];
    int d = ei[EE + e];
    int p = rs[d] + atomicAdd(&cnt[d], 1);
    ecw[p] = make_int2(s, __float_as_int(dinv[s]));
}

// ---------------------------------------------------------------------------
// W pack: swizzled LDS-image (unchanged)
// ---------------------------------------------------------------------------
__global__ void packw_kernel(const float* __restrict__ W1, const float* __restrict__ W2,
                             _Float16* __restrict__ wp) {
    int idx = blockIdx.x * 256 + threadIdx.x;   // 0..16383
    int p   = idx & 511;
    int kt  = (idx >> 9) & 7;
    int nb  = (idx >> 12) & 1;
    int L   = (idx >> 13) & 1;
    const float* W = L ? W2 : W1;
    int rs = p >> 2, cs = p & 3;
    int r  = rs ^ ((rs >> 2) & 1);
    int c  = cs ^ (r & 3);
    int n  = nb * 128 + r;
    int k0 = kt * 32 + c * 8;
    f16x8 hi, lo;
#pragma unroll
    for (int j = 0; j < 8; ++j) {
        float v = W[(size_t)(k0 + j) * 256 + n];
        _Float16 h = (_Float16)v;
        hi[j] = h;
        lo[j] = (_Float16)(v - (float)h);
    }
    size_t ch = ((size_t)((L * 2 + 0) * 2 + nb) * 8 + kt) * 4096;
    size_t cl = ((size_t)((L * 2 + 1) * 2 + nb) * 8 + kt) * 4096;
    *(f16x8*)(wp + ch + (size_t)p * 8) = hi;
    *(f16x8*)(wp + cl + (size_t)p * 8) = lo;
}

// ---------------------------------------------------------------------------
// GEMM. Output H is SLICE-MAJOR: Hs[slice][row][32] fp16, slice = n>>5.
// A input: AT=float  -> row-major [NN][256] fp32 (layer 1 input x)
//          AT=_Float16 -> slice-major [8][NN][32] (layer-1 agg output) --
//          note BK=32 == slice width, so k-tile kt reads exactly slice kt.
// Same-XCD pair swizzle for the two nb blocks sharing an A panel.
// ---------------------------------------------------------------------------

__device__ __forceinline__ void gll16(const void* g, void* l) {
    __builtin_amdgcn_global_load_lds(
        (const __attribute__((address_space(1))) void*)g,
        (__attribute__((address_space(3))) void*)l, 16, 0, 0);
}

template<typename AT>
__global__ __launch_bounds__(512) void gemm_kernel(
    const AT* __restrict__ X, const _Float16* __restrict__ Bhi,
    const _Float16* __restrict__ Blo, _Float16* __restrict__ H) {
    __shared__ __align__(16) _Float16 Bh[2][4096];   // 2 x 8KB
    __shared__ __align__(16) _Float16 Bl[2][4096];   // 2 x 8KB
    __shared__ __align__(16) AT       As[2][4096];   // fp32: 2x16KB, fp16: 2x8KB

    // de-swizzle linear block id -> (pair p, member nb) with same-XCD pairing
    const int gid = blockIdx.x;
    const int p_  = (gid >> 4) * 8 + (gid & 7);
    const int nb  = (gid >> 3) & 1;
    if (p_ >= 391) return;

    const int tid = threadIdx.x;
    const int ln  = tid & 63;
    const int w   = tid >> 6;        // 0..7
    const int wm  = w & 1;           // 2 x 64 rows
    const int wn  = w >> 1;          // 4 x 32 cols
    const int q   = ln >> 4;         // k-group
    const int l16 = ln & 15;
    const int m0  = p_ * 128;
    const size_t bchunk = (size_t)nb * 8 * 4096;

    f32x4 acc[4][2] = {};            // [mt][nt]

    auto stage = [&](int kt, int buf) {
        int g = w * 64 + ln;                       // granule 0..511
        gll16(Bhi + bchunk + (size_t)kt * 4096 + (size_t)g * 8,
              &Bh[buf][w * 512]);
        gll16(Blo + bchunk + (size_t)kt * 4096 + (size_t)g * 8,
              &Bl[buf][w * 512]);
        if constexpr (sizeof(AT) == 4) {
#pragma unroll
            for (int pp = 0; pp < 2; ++pp) {
                int gg = pp * 512 + w * 64 + ln;    // 0..1023
                int rss = gg >> 3, cs = gg & 7;
                int c  = cs ^ (rss & 7);
                int gm = m0 + rss; if (gm > NN - 1) gm = NN - 1;
                gll16((const float*)X + (size_t)gm * FF + kt * 32 + c * 4,
                      (float*)&As[buf][0] + (size_t)(pp * 512 + w * 64) * 4);
            }
        } else {
            // slice-major fp16 A: slice kt, row gm, within-slice offset c*8
            int rss = g >> 2, cs = g & 3;
            int r  = rss ^ ((rss >> 2) & 1);
            int c  = cs ^ (r & 3);
            int gm = m0 + r; if (gm > NN - 1) gm = NN - 1;
            gll16((const _Float16*)X + ((size_t)kt * NN + gm) * 32 + c * 8,
                  (_Float16*)&As[buf][0] + (size_t)(w * 64) * 8);
        }
    };

    auto compute = [&](int buf) {
        f16x8 af[4], bhf[2], blf[2];
#pragma unroll
        for (int mt = 0; mt < 4; ++mt) {
            int r = wm * 64 + mt * 16 + l16;
            if constexpr (sizeof(AT) == 4) {
                const float* Ab = (const float*)&As[buf][0];
                f32x4 v0 = *(const f32x4*)(Ab + (size_t)(r * 8 + ((2 * q)     ^ (r & 7))) * 4);
                f32x4 v1 = *(const f32x4*)(Ab + (size_t)(r * 8 + ((2 * q + 1) ^ (r & 7))) * 4);
                f16x8 a;
                a[0] = (_Float16)v0.x; a[1] = (_Float16)v0.y;
                a[2] = (_Float16)v0.z; a[3] = (_Float16)v0.w;
                a[4] = (_Float16)v1.x; a[5] = (_Float16)v1.y;
                a[6] = (_Float16)v1.z; a[7] = (_Float16)v1.w;
                af[mt] = a;
            } else {
                const _Float16* Ab = (const _Float16*)&As[buf][0];
                int rr = r ^ ((r >> 2) & 1);
                af[mt] = *(const f16x8*)(Ab + (size_t)(rr * 4 + (q ^ (r & 3))) * 8);
            }
        }
#pragma unroll
        for (int nt = 0; nt < 2; ++nt) {
            int r  = wn * 32 + nt * 16 + l16;
            int rr = r ^ ((r >> 2) & 1);
            int off = (rr * 4 + (q ^ (r & 3))) * 8;
            bhf[nt] = *(const f16x8*)(&Bh[buf][off]);
            blf[nt] = *(const f16x8*)(&Bl[buf][off]);
        }
#pragma unroll
        for (int mt = 0; mt < 4; ++mt)
#pragma unroll
            for (int nt = 0; nt < 2; ++nt) {
                acc[mt][nt] = __builtin_amdgcn_mfma_f32_16x16x32_f16(af[mt], bhf[nt], acc[mt][nt], 0, 0, 0);
                acc[mt][nt] = __builtin_amdgcn_mfma_f32_16x16x32_f16(af[mt], blf[nt], acc[mt][nt], 0, 0, 0);
            }
    };

    stage(0, 0);
    __syncthreads();
    int cur = 0;
#pragma unroll
    for (int kt = 0; kt < 8; ++kt) {
        if (kt < 7) stage(kt + 1, cur ^ 1);
        compute(cur);
        __syncthreads();
        cur ^= 1;
    }

    // epilogue: write slice-major. slice = nb*4+wn, within-slice n = nt*16+l16
    const int sl = nb * 4 + wn;
#pragma unroll
    for (int mt = 0; mt < 4; ++mt)
#pragma unroll
        for (int r4 = 0; r4 < 4; ++r4) {
            int m = m0 + wm * 64 + mt * 16 + q * 4 + r4;
            if (m < NN) {
#pragma unroll
                for (int nt = 0; nt < 2; ++nt) {
                    H[((size_t)sl * NN + m) * 32 + nt * 16 + l16] =
                        (_Float16)acc[mt][nt][r4];
                }
            }
        }
}

// ---------------------------------------------------------------------------
// Aggregation + bias + PReLU, XCD-resident feature slicing, v2.
// H is slice-major [8][NN][32] fp16: slice block = contiguous 3.2 MB,
// line-aligned -> fits one XCD's 4 MB L2 with zero line-split.
// slice = blockIdx & 7 (round-robin dispatch -> one slice per XCD).
// Wave = 4 rows; per row: 2 edge-subgroups x 8 feature-quads; each subgroup
// 4-unrolled -> 16 independent 64B gathers in flight per wave (MLP restored).
// ecw loads + output stores are nontemporal so streams don't evict the slice.
// ---------------------------------------------------------------------------
template<typename OT>
__global__ __launch_bounds__(256) void agg_kernel(
    const _Float16* __restrict__ Hs, const int* __restrict__ rs,
    const int2* __restrict__ ecw, const float* __restrict__ dinv,
    const float* __restrict__ bias, const float* __restrict__ a_ptr,
    OT* __restrict__ out) {
    const int slice = blockIdx.x & 7;
    const int lane  = threadIdx.x & 63;
    const int g     = (threadIdx.x >> 4) & 3;     // row-group within wave
    const int wv    = threadIdx.x >> 6;           // wave 0..3
    const int s     = (lane >> 3) & 1;            // edge subgroup
    const int t     = lane & 7;                   // feature quad (4 feats)
    const int row   = (blockIdx.x >> 3) * 16 + wv * 4 + g;
    if (row >= NN) return;

    const _Float16* Hsl = Hs + (size_t)slice * ((size_t)NN * 32);
    const float av = a_ptr[0];
    const float di = dinv[row];

    float ax = 0.f, ay = 0.f, az = 0.f, aw = 0.f;
    if (s == 0) {                                  // self-loop, counted once
        f16x4 hv = *(const f16x4*)(Hsl + (size_t)row * 32 + t * 4);
        ax = di * (float)hv.x; ay = di * (float)hv.y;
        az = di * (float)hv.z; aw = di * (float)hv.w;
    }

    int e = rs[row] + s;                           // subgroup takes e, e+2, ...
    const int end = rs[row + 1];
    for (; e + 6 < end; e += 8) {                  // 4 edges in flight
        long long q0 = __builtin_nontemporal_load((const long long*)(ecw + e));
        long long q1 = __builtin_nontemporal_load((const long long*)(ecw + e + 2));
        long long q2 = __builtin_nontemporal_load((const long long*)(ecw + e + 4));
        long long q3 = __builtin_nontemporal_load((const long long*)(ecw + e + 6));
        f16x4 h0 = *(const f16x4*)(Hsl + (size_t)(int)q0 * 32 + t * 4);
        f16x4 h1 = *(const f16x4*)(Hsl + (size_t)(int)q1 * 32 + t * 4);
        f16x4 h2 = *(const f16x4*)(Hsl + (size_t)(int)q2 * 32 + t * 4);
        f16x4 h3 = *(const f16x4*)(Hsl + (size_t)(int)q3 * 32 + t * 4);
        float w0 = __int_as_float((int)(q0 >> 32));
        float w1 = __int_as_float((int)(q1 >> 32));
        float w2 = __int_as_float((int)(q2 >> 32));
        float w3 = __int_as_float((int)(q3 >> 32));
        ax += w0 * (float)h0.x + w1 * (float)h1.x + w2 * (float)h2.x + w3 * (float)h3.x;
        ay += w0 * (float)h0.y + w1 * (float)h1.y + w2 * (float)h2.y + w3 * (float)h3.y;
        az += w0 * (float)h0.z + w1 * (float)h1.z + w2 * (float)h2.z + w3 * (float)h3.z;
        aw += w0 * (float)h0.w + w1 * (float)h1.w + w2 * (float)h2.w + w3 * (float)h3.w;
    }
    for (; e < end; e += 2) {
        long long q0 = __builtin_nontemporal_load((const long long*)(ecw + e));
        float w0 = __int_as_float((int)(q0 >> 32));
        f16x4 h0 = *(const f16x4*)(Hsl + (size_t)(int)q0 * 32 + t * 4);
        ax += w0 * (float)h0.x;
        ay += w0 * (float)h0.y;
        az += w0 * (float)h0.z;
        aw += w0 * (float)h0.w;
    }

    // combine the two subgroups (bit 3)
    ax += __shfl_xor(ax, 8);
    ay += __shfl_xor(ay, 8);
    az += __shfl_xor(az, 8);
    aw += __shfl_xor(aw, 8);

    if (s == 0) {
        f32x4 bv = *(const f32x4*)(bias + slice * 32 + t * 4);
        float r0 = di * ax + bv.x; r0 = (r0 >= 0.f) ? r0 : av * r0;
        float r1 = di * ay + bv.y; r1 = (r1 >= 0.f) ? r1 : av * r1;
        float r2 = di * az + bv.z; r2 = (r2 >= 0.f) ? r2 : av * r2;
        float r3 = di * aw + bv.w; r3 = (r3 >= 0.f) ? r3 : av * r3;
        if constexpr (sizeof(OT) == 4) {
            // final output: row-major fp32 [NN][256]
            float* p = (float*)out + (size_t)row * FF + slice * 32 + t * 4;
            __builtin_nontemporal_store(r0, p + 0);
            __builtin_nontemporal_store(r1, p + 1);
            __builtin_nontemporal_store(r2, p + 2);
            __builtin_nontemporal_store(r3, p + 3);
        } else {
            // intermediate: slice-major fp16 [8][NN][32] (feeds GEMM2)
            f16x4 res;
            res.x = (_Float16)r0; res.y = (_Float16)r1;
            res.z = (_Float16)r2; res.w = (_Float16)r3;
            long long* p = (long long*)((_Float16*)out +
                           ((size_t)slice * NN + row) * 32 + t * 4);
            __builtin_nontemporal_store(*(long long*)&res, p);
        }
    }
}

// ---------------------------------------------------------------------------
// Launch
// ---------------------------------------------------------------------------
extern "C" void kernel_launch(void* const* d_in, const int* in_sizes, int n_in,
                              void* d_out, int out_size, void* d_ws, size_t ws_size,
                              hipStream_t stream) {
    const float* x  = (const float*)d_in[0];
    const float* W1 = (const float*)d_in[1];
    const float* b1 = (const float*)d_in[2];
    const float* W2 = (const float*)d_in[3];
    const float* b2 = (const float*)d_in[4];
    const float* a  = (const float*)d_in[5];
    const int*   ei = (const int*)d_in[6];
    float* out = (float*)d_out;

    char* ws = (char*)d_ws;
    size_t off = 0;
    auto carve = [&](size_t bytes) -> char* {
        char* p = ws + off;
        off = (off + bytes + 255) & ~(size_t)255;
        return p;
    };
    int*      ec   = (int*)carve((size_t)NN * 4);
    int*      cnt  = (int*)carve((size_t)NN * 4);
    int*      rs   = (int*)carve((size_t)(NN + 1) * 4);
    float*    dinv = (float*)carve((size_t)NN * 4);
    int*      bsum = (int*)carve((size_t)NBLK * 4);
    int*      boff = (int*)carve((size_t)NBLK * 4);
    int2*     ecw  = (int2*)carve((size_t)EE * 8);
    _Float16* wp   = (_Float16*)carve((size_t)4 * 65536 * 2);
    _Float16* h    = (_Float16*)carve((size_t)NN * FF * 2);
    _Float16* h1   = (_Float16*)carve((size_t)NN * FF * 2);

    hipMemsetAsync(ec, 0, (size_t)NN * 4, stream);
    hipMemsetAsync(cnt, 0, (size_t)NN * 4, stream);

    count_kernel<<<(EE + 255) / 256, 256, 0, stream>>>(ei, ec);
    scan_part <<<NBLK, 256, 0, stream>>>(ec, bsum);
    scan_mid  <<<1, 256, 0, stream>>>(bsum, boff, rs);
    scan_final<<<NBLK, 256, 0, stream>>>(ec, boff, rs, dinv);
    fill_kernel<<<(EE + 255) / 256, 256, 0, stream>>>(ei, rs, cnt, dinv, ecw);
    packw_kernel<<<64, 256, 0, stream>>>(W1, W2, wp);

    // layer 1: GEMM (fp32 A, row-major) -> agg (fp16 slice-major out)
    gemm_kernel<float><<<784, 512, 0, stream>>>(x, wp, wp + 65536, h);
    agg_kernel<_Float16><<<3125 * 8, 256, 0, stream>>>(h, rs, ecw, dinv, b1, a, h1);
    // layer 2: GEMM (fp16 A, slice-major) -> agg (fp32 row-major final)
    gemm_kernel<_Float16><<<784, 512, 0, stream>>>(h1, wp + 131072, wp + 131072 + 65536, h);
    agg_kernel<float><<<3125 * 8, 256, 0, stream>>>(h, rs, ecw, dinv, b2, a, out);
}

// Round 4
// 403.799 us; speedup vs baseline: 1.5586x; 1.2141x over previous
//
#include <hip/hip_runtime.h>

// Problem constants
#define NN 50000
#define EE 800000
#define FF 256   // IN = HID = PROJ = 256
#define NBLK 196 // ceil(NN/256)

typedef float    f32x4 __attribute__((ext_vector_type(4)));
typedef _Float16 f16x8 __attribute__((ext_vector_type(8)));
typedef _Float16 f16x4 __attribute__((ext_vector_type(4)));

// ---------------------------------------------------------------------------
// CSR build kernels (unchanged)
// ---------------------------------------------------------------------------

__global__ void count_kernel(const int* __restrict__ ei, int* __restrict__ ec) {
    int e = blockIdx.x * 256 + threadIdx.x;
    if (e < EE) atomicAdd(&ec[ei[EE + e]], 1);
}

__global__ __launch_bounds__(256) void scan_part(const int* __restrict__ ec,
                                                 int* __restrict__ bsum) {
    int i = blockIdx.x * 256 + threadIdx.x;
    int v = (i < NN) ? ec[i] : 0;
#pragma unroll
    for (int d = 1; d < 64; d <<= 1) v += __shfl_xor(v, d);
    __shared__ int wt[4];
    int lane = threadIdx.x & 63, wid = threadIdx.x >> 6;
    if (lane == 0) wt[wid] = v;
    __syncthreads();
    if (threadIdx.x == 0)
        bsum[blockIdx.x] = wt[0] + wt[1] + wt[2] + wt[3];
}

__global__ __launch_bounds__(256) void scan_mid(const int* __restrict__ bsum,
                                                int* __restrict__ boff,
                                                int* __restrict__ rs) {
    const int t = threadIdx.x;
    int v = (t < NBLK) ? bsum[t] : 0;
    int lane = t & 63, wid = t >> 6;
    int x = v;
#pragma unroll
    for (int d = 1; d < 64; d <<= 1) {
        int u = __shfl_up(x, d);
        if (lane >= d) x += u;
    }
    __shared__ int wt[4];
    if (lane == 63) wt[wid] = x;
    __syncthreads();
    int add = 0;
    for (int wi = 0; wi < wid; ++wi) add += wt[wi];
    x += add;                                   // inclusive scan
    if (t < NBLK) boff[t] = x - v;              // exclusive
    if (t == NBLK - 1) rs[NN] = x;              // total == EE
}

__global__ __launch_bounds__(256) void scan_final(const int* __restrict__ ec,
                                                  const int* __restrict__ boff,
                                                  int* __restrict__ rs,
                                                  float* __restrict__ dinv) {
    int i = blockIdx.x * 256 + threadIdx.x;
    int v = (i < NN) ? ec[i] : 0;
    int lane = threadIdx.x & 63, wid = threadIdx.x >> 6;
    int x = v;
#pragma unroll
    for (int d = 1; d < 64; d <<= 1) {
        int u = __shfl_up(x, d);
        if (lane >= d) x += u;
    }
    __shared__ int wt[4];
    if (lane == 63) wt[wid] = x;
    __syncthreads();
    int add = 0;
    for (int wi = 0; wi < wid; ++wi) add += wt[wi];
    x += add;                                   // block-inclusive
    if (i < NN) {
        rs[i]   = x - v + boff[blockIdx.x];     // global exclusive
        dinv[i] = rsqrtf((float)(v + 1));       // deg = edges + self-loop
    }
}

__global__ void fill_kernel(const int* __restrict__ ei, const int* __restrict__ rs,
                            int* __restrict__ cnt, const float* __restrict__ dinv,
                            int2* __restrict__ ecw) {
    int e = blockIdx.x * 256 + threadIdx.x;
    if (e >= EE) return;
    int s = ei[e];
    int d = ei[EE + e];
    int p = rs[d] + atomicAdd(&cnt[d], 1);
    ecw[p] = make_int2(s, __float_as_int(dinv[s]));
}

// ---------------------------------------------------------------------------
// W pack: swizzled LDS-image (unchanged)
// ---------------------------------------------------------------------------
__global__ void packw_kernel(const float* __restrict__ W1, const float* __restrict__ W2,
                             _Float16* __restrict__ wp) {
    int idx = blockIdx.x * 256 + threadIdx.x;   // 0..16383
    int p   = idx & 511;
    int kt  = (idx >> 9) & 7;
    int nb  = (idx >> 12) & 1;
    int L   = (idx >> 13) & 1;
    const float* W = L ? W2 : W1;
    int rs = p >> 2, cs = p & 3;
    int r  = rs ^ ((rs >> 2) & 1);
    int c  = cs ^ (r & 3);
    int n  = nb * 128 + r;
    int k0 = kt * 32 + c * 8;
    f16x8 hi, lo;
#pragma unroll
    for (int j = 0; j < 8; ++j) {
        float v = W[(size_t)(k0 + j) * 256 + n];
        _Float16 h = (_Float16)v;
        hi[j] = h;
        lo[j] = (_Float16)(v - (float)h);
    }
    size_t ch = ((size_t)((L * 2 + 0) * 2 + nb) * 8 + kt) * 4096;
    size_t cl = ((size_t)((L * 2 + 1) * 2 + nb) * 8 + kt) * 4096;
    *(f16x8*)(wp + ch + (size_t)p * 8) = hi;
    *(f16x8*)(wp + cl + (size_t)p * 8) = lo;
}

// ---------------------------------------------------------------------------
// GEMM (unchanged from round 3). Output H is SLICE-MAJOR: Hs[slice][row][32].
// ---------------------------------------------------------------------------

__device__ __forceinline__ void gll16(const void* g, void* l) {
    __builtin_amdgcn_global_load_lds(
        (const __attribute__((address_space(1))) void*)g,
        (__attribute__((address_space(3))) void*)l, 16, 0, 0);
}

template<typename AT>
__global__ __launch_bounds__(512) void gemm_kernel(
    const AT* __restrict__ X, const _Float16* __restrict__ Bhi,
    const _Float16* __restrict__ Blo, _Float16* __restrict__ H) {
    __shared__ __align__(16) _Float16 Bh[2][4096];   // 2 x 8KB
    __shared__ __align__(16) _Float16 Bl[2][4096];   // 2 x 8KB
    __shared__ __align__(16) AT       As[2][4096];   // fp32: 2x16KB, fp16: 2x8KB

    const int gid = blockIdx.x;
    const int p_  = (gid >> 4) * 8 + (gid & 7);
    const int nb  = (gid >> 3) & 1;
    if (p_ >= 391) return;

    const int tid = threadIdx.x;
    const int ln  = tid & 63;
    const int w   = tid >> 6;        // 0..7
    const int wm  = w & 1;           // 2 x 64 rows
    const int wn  = w >> 1;          // 4 x 32 cols
    const int q   = ln >> 4;         // k-group
    const int l16 = ln & 15;
    const int m0  = p_ * 128;
    const size_t bchunk = (size_t)nb * 8 * 4096;

    f32x4 acc[4][2] = {};            // [mt][nt]

    auto stage = [&](int kt, int buf) {
        int g = w * 64 + ln;                       // granule 0..511
        gll16(Bhi + bchunk + (size_t)kt * 4096 + (size_t)g * 8,
              &Bh[buf][w * 512]);
        gll16(Blo + bchunk + (size_t)kt * 4096 + (size_t)g * 8,
              &Bl[buf][w * 512]);
        if constexpr (sizeof(AT) == 4) {
#pragma unroll
            for (int pp = 0; pp < 2; ++pp) {
                int gg = pp * 512 + w * 64 + ln;    // 0..1023
                int rss = gg >> 3, cs = gg & 7;
                int c  = cs ^ (rss & 7);
                int gm = m0 + rss; if (gm > NN - 1) gm = NN - 1;
                gll16((const float*)X + (size_t)gm * FF + kt * 32 + c * 4,
                      (float*)&As[buf][0] + (size_t)(pp * 512 + w * 64) * 4);
            }
        } else {
            int rss = g >> 2, cs = g & 3;
            int r  = rss ^ ((rss >> 2) & 1);
            int c  = cs ^ (r & 3);
            int gm = m0 + r; if (gm > NN - 1) gm = NN - 1;
            gll16((const _Float16*)X + ((size_t)kt * NN + gm) * 32 + c * 8,
                  (_Float16*)&As[buf][0] + (size_t)(w * 64) * 8);
        }
    };

    auto compute = [&](int buf) {
        f16x8 af[4], bhf[2], blf[2];
#pragma unroll
        for (int mt = 0; mt < 4; ++mt) {
            int r = wm * 64 + mt * 16 + l16;
            if constexpr (sizeof(AT) == 4) {
                const float* Ab = (const float*)&As[buf][0];
                f32x4 v0 = *(const f32x4*)(Ab + (size_t)(r * 8 + ((2 * q)     ^ (r & 7))) * 4);
                f32x4 v1 = *(const f32x4*)(Ab + (size_t)(r * 8 + ((2 * q + 1) ^ (r & 7))) * 4);
                f16x8 a;
                a[0] = (_Float16)v0.x; a[1] = (_Float16)v0.y;
                a[2] = (_Float16)v0.z; a[3] = (_Float16)v0.w;
                a[4] = (_Float16)v1.x; a[5] = (_Float16)v1.y;
                a[6] = (_Float16)v1.z; a[7] = (_Float16)v1.w;
                af[mt] = a;
            } else {
                const _Float16* Ab = (const _Float16*)&As[buf][0];
                int rr = r ^ ((r >> 2) & 1);
                af[mt] = *(const f16x8*)(Ab + (size_t)(rr * 4 + (q ^ (r & 3))) * 8);
            }
        }
#pragma unroll
        for (int nt = 0; nt < 2; ++nt) {
            int r  = wn * 32 + nt * 16 + l16;
            int rr = r ^ ((r >> 2) & 1);
            int off = (rr * 4 + (q ^ (r & 3))) * 8;
            bhf[nt] = *(const f16x8*)(&Bh[buf][off]);
            blf[nt] = *(const f16x8*)(&Bl[buf][off]);
        }
#pragma unroll
        for (int mt = 0; mt < 4; ++mt)
#pragma unroll
            for (int nt = 0; nt < 2; ++nt) {
                acc[mt][nt] = __builtin_amdgcn_mfma_f32_16x16x32_f16(af[mt], bhf[nt], acc[mt][nt], 0, 0, 0);
                acc[mt][nt] = __builtin_amdgcn_mfma_f32_16x16x32_f16(af[mt], blf[nt], acc[mt][nt], 0, 0, 0);
            }
    };

    stage(0, 0);
    __syncthreads();
    int cur = 0;
#pragma unroll
    for (int kt = 0; kt < 8; ++kt) {
        if (kt < 7) stage(kt + 1, cur ^ 1);
        compute(cur);
        __syncthreads();
        cur ^= 1;
    }

    const int sl = nb * 4 + wn;
#pragma unroll
    for (int mt = 0; mt < 4; ++mt)
#pragma unroll
        for (int r4 = 0; r4 < 4; ++r4) {
            int m = m0 + wm * 64 + mt * 16 + q * 4 + r4;
            if (m < NN) {
#pragma unroll
                for (int nt = 0; nt < 2; ++nt) {
                    H[((size_t)sl * NN + m) * 32 + nt * 16 + l16] =
                        (_Float16)acc[mt][nt][r4];
                }
            }
        }
}

// ---------------------------------------------------------------------------
// Aggregation + bias + PReLU, XCD-resident slicing + LDS-staged edge records.
// H slice-major [8][NN][32] fp16 -> each XCD's 3.2 MB slice is L2-resident.
// Block = 16 rows x 1 slice. The block's CSR range [rs[rb], rs[rb+16]) is
// contiguous: stage it into LDS with one parallel burst of NT loads (HBM
// latency paid once, off the critical path), then the gather loop chains
// only on LDS read (~fast) + L2-hit gather (~200 cy), 4 independent per lane.
// Chunked at 2048 records for input-independence. NN % 16 == 0 -> no row
// bounds check (all threads reach the barriers).
// ---------------------------------------------------------------------------
#define ECAP 2048

template<typename OT>
__global__ __launch_bounds__(256) void agg_kernel(
    const _Float16* __restrict__ Hs, const int* __restrict__ rs,
    const int2* __restrict__ ecw, const float* __restrict__ dinv,
    const float* __restrict__ bias, const float* __restrict__ a_ptr,
    OT* __restrict__ out) {
    __shared__ long long erec[ECAP];               // 16 KB

    const int slice = blockIdx.x & 7;
    const int rb    = (blockIdx.x >> 3) * 16;      // block's first row
    const int lane  = threadIdx.x & 63;
    const int wv    = threadIdx.x >> 6;            // wave 0..3
    const int g     = lane >> 4;                   // row within wave 0..3
    const int s     = (lane >> 3) & 1;             // edge subgroup
    const int t     = lane & 7;                    // feature quad (4 feats)
    const int row   = rb + wv * 4 + g;             // < NN always (50000%16==0)

    const _Float16* Hsl = Hs + (size_t)slice * ((size_t)NN * 32);
    const float av = a_ptr[0];
    const float di = dinv[row];

    const int e0   = rs[rb];
    const int e1   = rs[rb + 16];
    const int erow = rs[row];
    const int eend = rs[row + 1];

    float ax, ay, az, aw;
    {   // self-loop term (subgroup 0 only, counted once)
        f16x4 hv = *(const f16x4*)(Hsl + (size_t)row * 32 + t * 4);
        float m = (s == 0) ? di : 0.f;
        ax = m * (float)hv.x; ay = m * (float)hv.y;
        az = m * (float)hv.z; aw = m * (float)hv.w;
    }

    for (int cs = e0; cs < e1; cs += ECAP) {
        const int ce  = (cs + ECAP < e1) ? cs + ECAP : e1;
        const int cnt = ce - cs;
        __syncthreads();                            // prev chunk fully consumed
        for (int i = threadIdx.x; i < cnt; i += 256)
            erec[i] = __builtin_nontemporal_load((const long long*)(ecw + cs + i));
        __syncthreads();

        int a = (erow > cs) ? erow : cs;
        int b = (eend < ce) ? eend : ce;
        const int2* er = (const int2*)erec;
        int j = a + ((s - (a - erow)) & 1);         // parity-align to subgroup
        for (; j + 6 < b; j += 8) {                 // 4 edges in flight
            int2 p0 = er[j     - cs];
            int2 p1 = er[j + 2 - cs];
            int2 p2 = er[j + 4 - cs];
            int2 p3 = er[j + 6 - cs];
            f16x4 h0 = *(const f16x4*)(Hsl + (size_t)p0.x * 32 + t * 4);
            f16x4 h1 = *(const f16x4*)(Hsl + (size_t)p1.x * 32 + t * 4);
            f16x4 h2 = *(const f16x4*)(Hsl + (size_t)p2.x * 32 + t * 4);
            f16x4 h3 = *(const f16x4*)(Hsl + (size_t)p3.x * 32 + t * 4);
            float w0 = __int_as_float(p0.y), w1 = __int_as_float(p1.y);
            float w2 = __int_as_float(p2.y), w3 = __int_as_float(p3.y);
            ax += w0 * (float)h0.x + w1 * (float)h1.x + w2 * (float)h2.x + w3 * (float)h3.x;
            ay += w0 * (float)h0.y + w1 * (float)h1.y + w2 * (float)h2.y + w3 * (float)h3.y;
            az += w0 * (float)h0.z + w1 * (float)h1.z + w2 * (float)h2.z + w3 * (float)h3.z;
            aw += w0 * (float)h0.w + w1 * (float)h1.w + w2 * (float)h2.w + w3 * (float)h3.w;
        }
        for (; j < b; j += 2) {
            int2 p0 = er[j - cs];
            float w0 = __int_as_float(p0.y);
            f16x4 h0 = *(const f16x4*)(Hsl + (size_t)p0.x * 32 + t * 4);
            ax += w0 * (float)h0.x;
            ay += w0 * (float)h0.y;
            az += w0 * (float)h0.z;
            aw += w0 * (float)h0.w;
        }
    }

    // combine the two subgroups (bit 3)
    ax += __shfl_xor(ax, 8);
    ay += __shfl_xor(ay, 8);
    az += __shfl_xor(az, 8);
    aw += __shfl_xor(aw, 8);

    if (s == 0) {
        f32x4 bv = *(const f32x4*)(bias + slice * 32 + t * 4);
        float r0 = di * ax + bv.x; r0 = (r0 >= 0.f) ? r0 : av * r0;
        float r1 = di * ay + bv.y; r1 = (r1 >= 0.f) ? r1 : av * r1;
        float r2 = di * az + bv.z; r2 = (r2 >= 0.f) ? r2 : av * r2;
        float r3 = di * aw + bv.w; r3 = (r3 >= 0.f) ? r3 : av * r3;
        if constexpr (sizeof(OT) == 4) {
            float* p = (float*)out + (size_t)row * FF + slice * 32 + t * 4;
            __builtin_nontemporal_store(r0, p + 0);
            __builtin_nontemporal_store(r1, p + 1);
            __builtin_nontemporal_store(r2, p + 2);
            __builtin_nontemporal_store(r3, p + 3);
        } else {
            f16x4 res;
            res.x = (_Float16)r0; res.y = (_Float16)r1;
            res.z = (_Float16)r2; res.w = (_Float16)r3;
            long long* p = (long long*)((_Float16*)out +
                           ((size_t)slice * NN + row) * 32 + t * 4);
            __builtin_nontemporal_store(*(long long*)&res, p);
        }
    }
}

// ---------------------------------------------------------------------------
// Launch
// ---------------------------------------------------------------------------
extern "C" void kernel_launch(void* const* d_in, const int* in_sizes, int n_in,
                              void* d_out, int out_size, void* d_ws, size_t ws_size,
                              hipStream_t stream) {
    const float* x  = (const float*)d_in[0];
    const float* W1 = (const float*)d_in[1];
    const float* b1 = (const float*)d_in[2];
    const float* W2 = (const float*)d_in[3];
    const float* b2 = (const float*)d_in[4];
    const float* a  = (const float*)d_in[5];
    const int*   ei = (const int*)d_in[6];
    float* out = (float*)d_out;

    char* ws = (char*)d_ws;
    size_t off = 0;
    auto carve = [&](size_t bytes) -> char* {
        char* p = ws + off;
        off = (off + bytes + 255) & ~(size_t)255;
        return p;
    };
    int*      ec   = (int*)carve((size_t)NN * 4);
    int*      cnt  = (int*)carve((size_t)NN * 4);
    int*      rs   = (int*)carve((size_t)(NN + 1) * 4);
    float*    dinv = (float*)carve((size_t)NN * 4);
    int*      bsum = (int*)carve((size_t)NBLK * 4);
    int*      boff = (int*)carve((size_t)NBLK * 4);
    int2*     ecw  = (int2*)carve((size_t)EE * 8);
    _Float16* wp   = (_Float16*)carve((size_t)4 * 65536 * 2);
    _Float16* h    = (_Float16*)carve((size_t)NN * FF * 2);
    _Float16* h1   = (_Float16*)carve((size_t)NN * FF * 2);

    hipMemsetAsync(ec, 0, (size_t)NN * 4, stream);
    hipMemsetAsync(cnt, 0, (size_t)NN * 4, stream);

    count_kernel<<<(EE + 255) / 256, 256, 0, stream>>>(ei, ec);
    scan_part <<<NBLK, 256, 0, stream>>>(ec, bsum);
    scan_mid  <<<1, 256, 0, stream>>>(bsum, boff, rs);
    scan_final<<<NBLK, 256, 0, stream>>>(ec, boff, rs, dinv);
    fill_kernel<<<(EE + 255) / 256, 256, 0, stream>>>(ei, rs, cnt, dinv, ecw);
    packw_kernel<<<64, 256, 0, stream>>>(W1, W2, wp);

    // layer 1: GEMM (fp32 A, row-major) -> agg (fp16 slice-major out)
    gemm_kernel<float><<<784, 512, 0, stream>>>(x, wp, wp + 65536, h);
    agg_kernel<_Float16><<<3125 * 8, 256, 0, stream>>>(h, rs, ecw, dinv, b1, a, h1);
    // layer 2: GEMM (fp16 A, slice-major) -> agg (fp32 row-major final)
    gemm_kernel<_Float16><<<784, 512, 0, stream>>>(h1, wp + 131072, wp + 131072 + 65536, h);
    agg_kernel<float><<<3125 * 8, 256, 0, stream>>>(h, rs, ecw, dinv, b2, a, out);
}